// Round 1
// baseline (457.227 us; speedup 1.0000x reference)
//
#include <hip/hip_runtime.h>
#include <cstddef>

#define BATCH 4
#define CH    16
#define HH    512
#define WW    512
#define HID   128
#define K3    48   // 3*CH

// One block per (b, row). 256 threads, each handles 2 pixels: j = tid, tid+256.
// Weights live in LDS; per-o reads are wave-uniform (broadcast, conflict-free).
__global__ __launch_bounds__(256, 2)
void ca_fused_f32(const float* __restrict__ x, const float* __restrict__ w0,
                  const float* __restrict__ b0, const float* __restrict__ w1,
                  const float* __restrict__ ru, float* __restrict__ out)
{
    __shared__ float s_w0[HID * K3];   // [o][k]
    __shared__ float s_w1t[HID * CH];  // [o][c]  (transposed w1)
    __shared__ float s_b0[HID];

    const int tid = threadIdx.x;
    for (int idx = tid; idx < HID * K3; idx += 256) s_w0[idx] = w0[idx];
    for (int idx = tid; idx < HID * CH; idx += 256) {
        const int o = idx >> 4, c = idx & 15;
        s_w1t[idx] = w1[c * HID + o];
    }
    if (tid < HID) s_b0[tid] = b0[tid];
    __syncthreads();

    const int row = blockIdx.x;      // 0 .. BATCH*HH-1
    const int b   = row / HH;
    const int i   = row % HH;

    const size_t plane = (size_t)HH * WW;
    const float* xb = x + (size_t)b * CH * plane + (size_t)i * WW;

    const bool up = (i > 0), dn = (i < HH - 1);   // block-uniform branches

    // ---- Sobel features: y[p][0..15]=x, [16..31]=grad_x, [32..47]=grad_y ----
    float y[2][K3];
    #pragma unroll
    for (int p = 0; p < 2; ++p) {
        const int j = tid + p * 256;
        const bool lf = (j > 0), rt = (j < WW - 1);
        #pragma unroll
        for (int c = 0; c < CH; ++c) {
            const float* xc = xb + (size_t)c * plane + j;
            const float xm = xc[0];
            const float xl = lf ? xc[-1] : 0.f;
            const float xr = rt ? xc[1]  : 0.f;
            float xu = 0.f, xul = 0.f, xur = 0.f;
            float xd = 0.f, xdl = 0.f, xdr = 0.f;
            if (up) {
                xu  = xc[-WW];
                xul = lf ? xc[-WW - 1] : 0.f;
                xur = rt ? xc[-WW + 1] : 0.f;
            }
            if (dn) {
                xd  = xc[WW];
                xdl = lf ? xc[WW - 1] : 0.f;
                xdr = rt ? xc[WW + 1] : 0.f;
            }
            y[p][c]          = xm;
            // cross-correlation (XLA conv does not flip kernels)
            y[p][CH + c]     = (xur - xul) + 2.f * (xr - xl) + (xdr - xdl);
            y[p][2 * CH + c] = (xdl - xul) + 2.f * (xd - xu) + (xdr - xur);
        }
    }

    // ---- MLP: h = relu(y @ w0^T + b0); upd = h @ w1^T ----
    float upd[2][CH];
    #pragma unroll
    for (int p = 0; p < 2; ++p)
        #pragma unroll
        for (int c = 0; c < CH; ++c) upd[p][c] = 0.f;

    for (int o = 0; o < HID; ++o) {
        // dual accumulators per pixel to break the 48-deep FMA chain
        float h0a = s_b0[o], h0b = 0.f;
        float h1a = h0a,     h1b = 0.f;
        const float4* w0r = (const float4*)&s_w0[o * K3];
        #pragma unroll
        for (int k4 = 0; k4 < K3 / 4; ++k4) {
            const float4 w = w0r[k4];
            if (k4 & 1) {
                h0b = fmaf(y[0][4 * k4 + 0], w.x, h0b);
                h0b = fmaf(y[0][4 * k4 + 1], w.y, h0b);
                h0b = fmaf(y[0][4 * k4 + 2], w.z, h0b);
                h0b = fmaf(y[0][4 * k4 + 3], w.w, h0b);
                h1b = fmaf(y[1][4 * k4 + 0], w.x, h1b);
                h1b = fmaf(y[1][4 * k4 + 1], w.y, h1b);
                h1b = fmaf(y[1][4 * k4 + 2], w.z, h1b);
                h1b = fmaf(y[1][4 * k4 + 3], w.w, h1b);
            } else {
                h0a = fmaf(y[0][4 * k4 + 0], w.x, h0a);
                h0a = fmaf(y[0][4 * k4 + 1], w.y, h0a);
                h0a = fmaf(y[0][4 * k4 + 2], w.z, h0a);
                h0a = fmaf(y[0][4 * k4 + 3], w.w, h0a);
                h1a = fmaf(y[1][4 * k4 + 0], w.x, h1a);
                h1a = fmaf(y[1][4 * k4 + 1], w.y, h1a);
                h1a = fmaf(y[1][4 * k4 + 2], w.z, h1a);
                h1a = fmaf(y[1][4 * k4 + 3], w.w, h1a);
            }
        }
        const float h0 = fmaxf(h0a + h0b, 0.f);
        const float h1 = fmaxf(h1a + h1b, 0.f);

        const float4* w1r = (const float4*)&s_w1t[o * CH];
        #pragma unroll
        for (int c4 = 0; c4 < CH / 4; ++c4) {
            const float4 w = w1r[c4];
            upd[0][4 * c4 + 0] = fmaf(h0, w.x, upd[0][4 * c4 + 0]);
            upd[0][4 * c4 + 1] = fmaf(h0, w.y, upd[0][4 * c4 + 1]);
            upd[0][4 * c4 + 2] = fmaf(h0, w.z, upd[0][4 * c4 + 2]);
            upd[0][4 * c4 + 3] = fmaf(h0, w.w, upd[0][4 * c4 + 3]);
            upd[1][4 * c4 + 0] = fmaf(h1, w.x, upd[1][4 * c4 + 0]);
            upd[1][4 * c4 + 1] = fmaf(h1, w.y, upd[1][4 * c4 + 1]);
            upd[1][4 * c4 + 2] = fmaf(h1, w.z, upd[1][4 * c4 + 2]);
            upd[1][4 * c4 + 3] = fmaf(h1, w.w, upd[1][4 * c4 + 3]);
        }
    }

    // ---- epilogue: out = x + upd * mask ----
    #pragma unroll
    for (int p = 0; p < 2; ++p) {
        const int j = tid + p * 256;
        const float r = ru[(size_t)b * plane + (size_t)i * WW + j];
        const float m = (r > 0.5f) ? 1.f : 0.f;
        float* ob = out + (size_t)b * CH * plane + (size_t)i * WW + j;
        #pragma unroll
        for (int c = 0; c < CH; ++c)
            ob[(size_t)c * plane] = fmaf(upd[p][c], m, y[p][c]);
    }
}

extern "C" void kernel_launch(void* const* d_in, const int* in_sizes, int n_in,
                              void* d_out, int out_size, void* d_ws, size_t ws_size,
                              hipStream_t stream) {
    const float* x  = (const float*)d_in[0];
    const float* w0 = (const float*)d_in[1];
    const float* b0 = (const float*)d_in[2];
    const float* w1 = (const float*)d_in[3];
    const float* ru = (const float*)d_in[4];
    float* out = (float*)d_out;

    dim3 grid(BATCH * HH);   // 2048 blocks: one per (batch, row)
    dim3 block(256);
    hipLaunchKernelGGL(ca_fused_f32, grid, block, 0, stream, x, w0, b0, w1, ru, out);
}

// Round 2
// 311.121 us; speedup vs baseline: 1.4696x; 1.4696x over previous
//
#include <hip/hip_runtime.h>
#include <cstddef>

#define BATCH 4
#define CH    16
#define HH    512
#define WW    512
#define HID   128
#define K3    48      // 3*CH
#define YSTR  72      // sY row stride in bf16 (48 feats + 16 pad-K + 8 bank-pad)
#define HSTR  136     // sH row stride in bf16 (128 + 8 bank-pad)

typedef __bf16 bf16x8 __attribute__((ext_vector_type(8)));
typedef __bf16 bf16x4 __attribute__((ext_vector_type(4)));
typedef float  f32x4  __attribute__((ext_vector_type(4)));

static __device__ __forceinline__ f32x4 mfma16(bf16x8 a, bf16x8 b, f32x4 c) {
    return __builtin_amdgcn_mfma_f32_16x16x32_bf16(a, b, c, 0, 0, 0);
}

// One block per (b, image row). 256 threads = 4 waves; block sweeps the row in
// 8 segments of 64 pixels; each wave owns a 16-pixel MFMA tile per segment.
// W0 (+bias as K=48 feature) and W1 live in registers as A-fragments for the
// whole row. Sobel features -> LDS (bf16, B-fragment-friendly layout) ->
// GEMM1 (16 MFMA) -> relu -> LDS -> GEMM2 (4 MFMA) -> masked residual store.
__global__ __launch_bounds__(256, 2)
void ca_mfma(const float* __restrict__ x, const float* __restrict__ w0,
             const float* __restrict__ b0, const float* __restrict__ w1,
             const float* __restrict__ ru, float* __restrict__ out)
{
    __shared__ __align__(16) __bf16 sY[64 * YSTR];   // [px][feature]
    __shared__ __align__(16) __bf16 sH[64 * HSTR];   // [px][hidden], wave-private rows

    const int tid  = threadIdx.x;
    const int lane = tid & 63;
    const int wv   = tid >> 6;     // wave 0..3
    const int p    = lane & 15;    // MFMA m (A) / n (B,D) index
    const int q    = lane >> 4;    // quad 0..3

    const int row = blockIdx.x;    // 0 .. BATCH*HH-1
    const int b   = row >> 9;
    const int i   = row & (HH - 1);

    // ---- A-fragments: W0 (two K-steps; step1 carries b0 at k==48) ----
    // A[m=lane&15][k=8*q+j] per 16x16x32 layout (m120-verified).
    bf16x8 a0[8], a1[8];
    #pragma unroll
    for (int t = 0; t < 8; ++t) {
        const int o = 16 * t + p;
        #pragma unroll
        for (int j = 0; j < 8; ++j) {
            const int k0 = 8 * q + j;            // 0..31, always valid
            a0[t][j] = (__bf16)w0[o * K3 + k0];
            const int k1 = 32 + 8 * q + j;       // 32..63
            float v;
            if (k1 < K3)       v = w0[o * K3 + k1];
            else if (k1 == K3) v = b0[o];        // bias via Y[48] = 1.0
            else               v = 0.f;
            a1[t][j] = (__bf16)v;
        }
    }
    // ---- A-fragments: W1 [16 x 128], 4 K-steps ----
    bf16x8 aw1[4];
    #pragma unroll
    for (int s = 0; s < 4; ++s)
        #pragma unroll
        for (int j = 0; j < 8; ++j)
            aw1[s][j] = (__bf16)w1[p * HID + 32 * s + 8 * q + j];

    // ---- static K-pad of sY: features 48..63 (48 itself = 1.0 bias feature) ----
    {
        const int px = tid & 63, g = tid >> 6;
        bf16x4 z;
        z[0] = (__bf16)((g == 0) ? 1.0f : 0.0f);
        z[1] = (__bf16)0.f; z[2] = (__bf16)0.f; z[3] = (__bf16)0.f;
        *(bf16x4*)&sY[px * YSTR + 48 + 4 * g] = z;
    }

    const bool   up    = (i > 0), dn = (i < HH - 1);
    const size_t plane = (size_t)HH * WW;
    const float* xb    = x + (size_t)b * CH * plane + (size_t)i * WW;

    for (int seg = 0; seg < 8; ++seg) {
        const int j0 = seg * 64;

        // ---- feature build: thread (px = tid&63) does 4 channels ----
        {
            const int px = tid & 63;
            const int j  = j0 + px;
            const bool lf = (j > 0), rt = (j < WW - 1);
            #pragma unroll
            for (int k = 0; k < 4; ++k) {
                const int ch = 4 * wv + k;
                const float* c0 = xb + (size_t)ch * plane + j;
                const float xm = c0[0];
                const float xl = lf ? c0[-1] : 0.f;
                const float xr = rt ? c0[1]  : 0.f;
                float xu = 0.f, xul = 0.f, xur = 0.f;
                float xd = 0.f, xdl = 0.f, xdr = 0.f;
                if (up) {
                    xu  = c0[-WW];
                    xul = lf ? c0[-WW - 1] : 0.f;
                    xur = rt ? c0[-WW + 1] : 0.f;
                }
                if (dn) {
                    xd  = c0[WW];
                    xdl = lf ? c0[WW - 1] : 0.f;
                    xdr = rt ? c0[WW + 1] : 0.f;
                }
                const float gx = (xur - xul) + 2.f * (xr - xl) + (xdr - xdl);
                const float gy = (xdl - xul) + 2.f * (xd - xu) + (xdr - xur);
                sY[px * YSTR + ch]          = (__bf16)xm;
                sY[px * YSTR + CH + ch]     = (__bf16)gx;
                sY[px * YSTR + 2 * CH + ch] = (__bf16)gy;
            }
        }
        __syncthreads();

        // ---- MFMA phase: wave wv owns pixels 16*wv .. 16*wv+15 ----
        const int pxg = 16 * wv + p;   // this lane's pixel column (B/D n-index)

        const bf16x8 yb0 = *(const bf16x8*)&sY[pxg * YSTR + 8 * q];
        const bf16x8 yb1 = *(const bf16x8*)&sY[pxg * YSTR + 32 + 8 * q];

        f32x4 acc[8];
        #pragma unroll
        for (int t = 0; t < 8; ++t) {
            acc[t] = f32x4{0.f, 0.f, 0.f, 0.f};
            acc[t] = mfma16(a0[t], yb0, acc[t]);
            acc[t] = mfma16(a1[t], yb1, acc[t]);
        }

        // relu + cvt -> sH[pxg][o], o = 16t + 4q + r  (D: col=n=px, row=4q+r)
        #pragma unroll
        for (int t = 0; t < 8; ++t) {
            bf16x4 hv;
            #pragma unroll
            for (int r = 0; r < 4; ++r)
                hv[r] = (__bf16)fmaxf(acc[t][r], 0.f);
            *(bf16x4*)&sH[pxg * HSTR + 16 * t + 4 * q] = hv;
        }
        // same-wave LDS write->read: in-order per wave, no barrier needed

        f32x4 u = f32x4{0.f, 0.f, 0.f, 0.f};
        #pragma unroll
        for (int s = 0; s < 4; ++s) {
            const bf16x8 hb = *(const bf16x8*)&sH[pxg * HSTR + 32 * s + 8 * q];
            u = mfma16(aw1[s], hb, u);
        }

        // ---- epilogue: out[c][j] = x[c][j] + u[r]*mask, c = 4q + r ----
        const int jg = j0 + pxg;
        const float rv = ru[(size_t)b * plane + (size_t)i * WW + jg];
        const float m  = (rv > 0.5f) ? 1.f : 0.f;
        const float* xe = xb + jg;
        float* ob = out + (size_t)b * CH * plane + (size_t)i * WW + jg;
        #pragma unroll
        for (int r = 0; r < 4; ++r) {
            const int c = 4 * q + r;
            ob[(size_t)c * plane] = fmaf(u[r], m, xe[(size_t)c * plane]);
        }
        __syncthreads();   // protect sY against next segment's build
    }
}

extern "C" void kernel_launch(void* const* d_in, const int* in_sizes, int n_in,
                              void* d_out, int out_size, void* d_ws, size_t ws_size,
                              hipStream_t stream) {
    const float* x  = (const float*)d_in[0];
    const float* w0 = (const float*)d_in[1];
    const float* b0 = (const float*)d_in[2];
    const float* w1 = (const float*)d_in[3];
    const float* ru = (const float*)d_in[4];
    float* out = (float*)d_out;

    dim3 grid(BATCH * HH);   // 2048 blocks: one per (batch, image row)
    dim3 block(256);
    hipLaunchKernelGGL(ca_mfma, grid, block, 0, stream, x, w0, b0, w1, ru, out);
}

// Round 3
// 263.888 us; speedup vs baseline: 1.7327x; 1.1790x over previous
//
#include <hip/hip_runtime.h>
#include <cstddef>

#define BATCH 4
#define CH    16
#define HH    512
#define WW    512
#define HID   128
#define K3    48      // 3*CH
#define YSTR  72      // sY row stride (48 feats + 16 K-pad + 8 bank-pad), 144 B
#define HSTR  136     // sH row stride (128 + 8 bank-pad), 272 B
#define XSTR  17      // sXC row stride in fp32 (odd -> conflict-free)

typedef __bf16 bf16x8 __attribute__((ext_vector_type(8)));
typedef __bf16 bf16x4 __attribute__((ext_vector_type(4)));
typedef float  f32x4  __attribute__((ext_vector_type(4)));

static __device__ __forceinline__ f32x4 mfma16(bf16x8 a, bf16x8 b, f32x4 c) {
    return __builtin_amdgcn_mfma_f32_16x16x32_bf16(a, b, c, 0, 0, 0);
}

// One block per (b, image row); 8 segments of 64 px. Weights live in LDS in
// frag-ordered layout (freeing ~80 VGPRs so the 36-load stencil stays fully
// in flight). Loads for segment s+1 are issued during segment s's MFMA phase
// and consumed just before the next barrier: prefetch distance = one phase.
__global__ __launch_bounds__(256, 3)
void ca_mfma3(const float* __restrict__ x, const float* __restrict__ w0,
              const float* __restrict__ b0, const float* __restrict__ w1,
              const float* __restrict__ ru, float* __restrict__ out)
{
    // frag-ordered weights: sW0[ks][t][lane][8], sW1[s][lane][8]
    __shared__ __align__(16) __bf16 sW0[2 * 8 * 64 * 8];   // 16 KB
    __shared__ __align__(16) __bf16 sW1[4 * 64 * 8];       //  4 KB
    __shared__ __align__(16) __bf16 sY[64 * YSTR];         // 9.0 KB
    __shared__ __align__(16) __bf16 sH[64 * HSTR];         // 17.0 KB
    __shared__ float sXC[64 * XSTR];                       // 4.25 KB

    const int tid  = threadIdx.x;
    const int lane = tid & 63;
    const int wv   = tid >> 6;
    const int p    = lane & 15;   // MFMA m/n index
    const int q    = lane >> 4;   // quad

    const int row = blockIdx.x;
    const int b   = row >> 9;
    const int i   = row & (HH - 1);

    // ---- stage W0 (+bias at k==48) into LDS, frag-ordered ----
    for (int e = tid; e < 1024; e += 256) {
        const int ks = e >> 9, rem = e & 511;
        const int t = rem >> 6, ln = rem & 63;
        const int pp = ln & 15, qq = ln >> 4;
        const int o = 16 * t + pp;
        bf16x8 v;
        #pragma unroll
        for (int j = 0; j < 8; ++j) {
            const int k = 32 * ks + 8 * qq + j;
            float val;
            if (k < K3)       val = w0[o * K3 + k];
            else if (k == K3) val = b0[o];
            else              val = 0.f;
            v[j] = (__bf16)val;
        }
        *(bf16x8*)&sW0[e * 8] = v;
    }
    // ---- stage W1 [16 x 128] frag-ordered: one entry per thread ----
    {
        const int e = tid;                 // 256 entries total
        const int s = e >> 6, ln = e & 63;
        const int pp = ln & 15, qq = ln >> 4;
        bf16x8 v;
        #pragma unroll
        for (int j = 0; j < 8; ++j)
            v[j] = (__bf16)w1[pp * HID + 32 * s + 8 * qq + j];
        *(bf16x8*)&sW1[e * 8] = v;
    }
    // ---- static K-pad of sY: feature 48 = 1.0 (bias), 49..63 = 0 ----
    if (tid < 64) {
        bf16x8 z0, z1;
        #pragma unroll
        for (int j = 0; j < 8; ++j) { z0[j] = (__bf16)0.f; z1[j] = (__bf16)0.f; }
        z0[0] = (__bf16)1.0f;
        *(bf16x8*)&sY[tid * YSTR + 48] = z0;
        *(bf16x8*)&sY[tid * YSTR + 56] = z1;
    }
    __syncthreads();

    const size_t plane = (size_t)HH * WW;
    const float* xb    = x + (size_t)b * CH * plane + (size_t)i * WW;
    const bool   up    = (i > 0), dn = (i < HH - 1);
    const int    px    = tid & 63;        // feature-build pixel

    // stencil load buffer: [ch 0..3][ul,u,ur, l,m,r, dl,d,dr]
    float L[4][9];
    auto issue_loads = [&](int s) {
        const int j  = s * 64 + px;
        const bool lf = (j > 0), rt = (j < WW - 1);
        #pragma unroll
        for (int k = 0; k < 4; ++k) {
            const float* c0 = xb + (size_t)(4 * wv + k) * plane + j;
            L[k][0] = (up && lf) ? c0[-WW - 1] : 0.f;
            L[k][1] =  up        ? c0[-WW]     : 0.f;
            L[k][2] = (up && rt) ? c0[-WW + 1] : 0.f;
            L[k][3] =  lf        ? c0[-1]      : 0.f;
            L[k][4] =              c0[0];
            L[k][5] =  rt        ? c0[1]       : 0.f;
            L[k][6] = (dn && lf) ? c0[WW - 1]  : 0.f;
            L[k][7] =  dn        ? c0[WW]      : 0.f;
            L[k][8] = (dn && rt) ? c0[WW + 1]  : 0.f;
        }
    };

    issue_loads(0);

    for (int s = 0; s < 8; ++s) {
        // ---- compute Sobel features from in-flight loads (VALU only) ----
        float fm[4], fx[4], fy[4];
        #pragma unroll
        for (int k = 0; k < 4; ++k) {
            fm[k] = L[k][4];
            fx[k] = (L[k][2] - L[k][0]) + 2.f * (L[k][5] - L[k][3]) + (L[k][8] - L[k][6]);
            fy[k] = (L[k][6] - L[k][0]) + 2.f * (L[k][7] - L[k][1]) + (L[k][8] - L[k][2]);
        }
        __syncthreads();   // #A: all waves done reading sY/sXC of segment s-1
        #pragma unroll
        for (int k = 0; k < 4; ++k) {
            const int ch = 4 * wv + k;
            sY[px * YSTR + ch]          = (__bf16)fm[k];
            sY[px * YSTR + CH + ch]     = (__bf16)fx[k];
            sY[px * YSTR + 2 * CH + ch] = (__bf16)fy[k];
            sXC[px * XSTR + ch]         = fm[k];
        }
        __syncthreads();   // #B: writes visible

        if (s < 7) issue_loads(s + 1);   // in flight across MFMA + epilogue

        // ---- MFMA phase: wave wv owns pixels 16*wv .. 16*wv+15 ----
        const int pxg = 16 * wv + p;
        const bf16x8 yb0 = *(const bf16x8*)&sY[pxg * YSTR + 8 * q];
        const bf16x8 yb1 = *(const bf16x8*)&sY[pxg * YSTR + 32 + 8 * q];

        f32x4 acc[8];
        #pragma unroll
        for (int t = 0; t < 8; ++t) {
            const bf16x8 a0 = *(const bf16x8*)&sW0[((0 * 8 + t) * 64 + lane) * 8];
            const bf16x8 a1 = *(const bf16x8*)&sW0[((1 * 8 + t) * 64 + lane) * 8];
            acc[t] = f32x4{0.f, 0.f, 0.f, 0.f};
            acc[t] = mfma16(a0, yb0, acc[t]);
            acc[t] = mfma16(a1, yb1, acc[t]);
        }
        // relu + cvt -> sH[pxg][o], o = 16t + 4q + r (D-layout: col=px, row=4q+r)
        #pragma unroll
        for (int t = 0; t < 8; ++t) {
            bf16x4 hv;
            #pragma unroll
            for (int r = 0; r < 4; ++r)
                hv[r] = (__bf16)fmaxf(acc[t][r], 0.f);
            *(bf16x4*)&sH[pxg * HSTR + 16 * t + 4 * q] = hv;
        }
        // same-wave LDS write->read, wave-private rows: no barrier needed
        f32x4 u = f32x4{0.f, 0.f, 0.f, 0.f};
        #pragma unroll
        for (int ss = 0; ss < 4; ++ss) {
            const bf16x8 hb = *(const bf16x8*)&sH[pxg * HSTR + 32 * ss + 8 * q];
            const bf16x8 aw = *(const bf16x8*)&sW1[(ss * 64 + lane) * 8];
            u = mfma16(aw, hb, u);
        }

        // ---- epilogue: out[c][jg] = xc + u[r]*mask, c = 4q + r ----
        const int jg = s * 64 + pxg;
        const float rv = ru[(size_t)b * plane + (size_t)i * WW + jg];
        const float m  = (rv > 0.5f) ? 1.f : 0.f;
        float* ob = out + (size_t)b * CH * plane + (size_t)i * WW + jg;
        #pragma unroll
        for (int r = 0; r < 4; ++r) {
            const int c = 4 * q + r;
            ob[(size_t)c * plane] = fmaf(u[r], m, sXC[pxg * XSTR + c]);
        }
    }
}

extern "C" void kernel_launch(void* const* d_in, const int* in_sizes, int n_in,
                              void* d_out, int out_size, void* d_ws, size_t ws_size,
                              hipStream_t stream) {
    const float* x  = (const float*)d_in[0];
    const float* w0 = (const float*)d_in[1];
    const float* b0 = (const float*)d_in[2];
    const float* w1 = (const float*)d_in[3];
    const float* ru = (const float*)d_in[4];
    float* out = (float*)d_out;

    dim3 grid(BATCH * HH);   // 2048 blocks: one per (batch, image row)
    dim3 block(256);
    hipLaunchKernelGGL(ca_mfma3, grid, block, 0, stream, x, w0, b0, w1, ru, out);
}